// Round 2
// baseline (701.469 us; speedup 1.0000x reference)
//
#include <hip/hip_runtime.h>

// GHM Dice loss, 3 passes:
//  k_reduce1: I = sum(p*t), sumP, sumT                        (reads p,t)
//  k_pass2:   histogram counts[10] + binsum[10] of 2*p*t, tot (reads p,t,lw)
//  k_final:   combine scalars -> loss
//
// All float accumulation uses unsafeAtomicAdd (HW global_atomic_add_f32 /
// ds_add_f32). Default atomicAdd(float*) emits a CAS retry loop on gfx9 —
// with 2048 blocks contending on 3 addresses that was the 328+325 us stall
// in round 1 (VALUBusy 3.7%, hbm 7.7%: pure serialization).
//
// ws layout (floats): [0]=I [1]=sumP [2]=sumT [3]=tot [4..13]=counts [14..23]=binsum

constexpr int BINS  = 10;
constexpr int NCOPY = 64;   // one LDS sub-histogram per lane -> no intra-wave collisions
constexpr int SSTR  = 11;   // stride 11 coprime with 32 banks -> 2 lanes/bank (free)

__global__ __launch_bounds__(256) void k_reduce1(const float4* __restrict__ p,
                                                 const float4* __restrict__ t,
                                                 float* __restrict__ ws,
                                                 int n4, int n) {
    int idx    = blockIdx.x * blockDim.x + threadIdx.x;
    int stride = gridDim.x * blockDim.x;
    float sI = 0.f, sP = 0.f, sT = 0.f;
#pragma unroll 4
    for (int i = idx; i < n4; i += stride) {
        float4 pv = p[i];
        float4 tv = t[i];
        sI += pv.x * tv.x + pv.y * tv.y + pv.z * tv.z + pv.w * tv.w;
        sP += pv.x + pv.y + pv.z + pv.w;
        sT += tv.x + tv.y + tv.z + tv.w;
    }
    if (idx == 0) {  // scalar tail (n not multiple of 4)
        const float* pf = (const float*)p;
        const float* tf = (const float*)t;
        for (int i = n4 * 4; i < n; ++i) { sI += pf[i] * tf[i]; sP += pf[i]; sT += tf[i]; }
    }
#pragma unroll
    for (int o = 32; o > 0; o >>= 1) {
        sI += __shfl_down(sI, o);
        sP += __shfl_down(sP, o);
        sT += __shfl_down(sT, o);
    }
    __shared__ float rI[4], rP[4], rT[4];
    int wave = threadIdx.x >> 6, lane = threadIdx.x & 63;
    if (lane == 0) { rI[wave] = sI; rP[wave] = sP; rT[wave] = sT; }
    __syncthreads();
    if (threadIdx.x == 0) {
        unsafeAtomicAdd(&ws[0], rI[0] + rI[1] + rI[2] + rI[3]);
        unsafeAtomicAdd(&ws[1], rP[0] + rP[1] + rP[2] + rP[3]);
        unsafeAtomicAdd(&ws[2], rT[0] + rT[1] + rT[2] + rT[3]);
    }
}

__global__ __launch_bounds__(256) void k_pass2(const float4* __restrict__ p,
                                               const float4* __restrict__ t,
                                               const float4* __restrict__ lw,
                                               float* __restrict__ ws,
                                               int n4, int n) {
    __shared__ float s_cnt[NCOPY * SSTR];
    __shared__ float s_sum[NCOPY * SSTR];
    for (int i = threadIdx.x; i < NCOPY * SSTR; i += blockDim.x) { s_cnt[i] = 0.f; s_sum[i] = 0.f; }
    __syncthreads();

    const float scale    = 2.f * ws[0] / (ws[1] + ws[2]);  // 2I/S (L2-hit broadcast)
    const float edge_top = 1.0f + 1e-6f;

    int idx    = blockIdx.x * blockDim.x + threadIdx.x;
    int stride = gridDim.x * blockDim.x;
    int copy   = (threadIdx.x & 63) * SSTR;
    float vcount = 0.f;

#pragma unroll 2
    for (int i = idx; i < n4; i += stride) {
        float4 pv = p[i], tv = t[i], wv = lw[i];
        float pj[4] = {pv.x, pv.y, pv.z, pv.w};
        float tj[4] = {tv.x, tv.y, tv.z, tv.w};
        float wj[4] = {wv.x, wv.y, wv.z, wv.w};
#pragma unroll
        for (int j = 0; j < 4; ++j) {
            bool valid = wj[j] > 0.f;
            vcount += valid ? 1.f : 0.f;
            float g = fabsf(scale * pj[j] - tj[j]);
            if (valid && g < edge_top) {
                int b = (int)(g * 10.f);          // g >= 0, trunc == floor
                b = b > (BINS - 1) ? (BINS - 1) : b;
                unsafeAtomicAdd(&s_cnt[copy + b], 1.f);          // ds_add_f32
                unsafeAtomicAdd(&s_sum[copy + b], 2.f * pj[j] * tj[j]);
            }
        }
    }
    if (idx == 0) {  // scalar tail
        const float* pf = (const float*)p;
        const float* tf = (const float*)t;
        const float* wf = (const float*)lw;
        for (int i = n4 * 4; i < n; ++i) {
            bool valid = wf[i] > 0.f;
            vcount += valid ? 1.f : 0.f;
            float g = fabsf(scale * pf[i] - tf[i]);
            if (valid && g < edge_top) {
                int b = (int)(g * 10.f);
                b = b > (BINS - 1) ? (BINS - 1) : b;
                unsafeAtomicAdd(&s_cnt[copy + b], 1.f);
                unsafeAtomicAdd(&s_sum[copy + b], 2.f * pf[i] * tf[i]);
            }
        }
    }

#pragma unroll
    for (int o = 32; o > 0; o >>= 1) vcount += __shfl_down(vcount, o);
    __shared__ float rV[4];
    int wave = threadIdx.x >> 6, lane = threadIdx.x & 63;
    if (lane == 0) rV[wave] = vcount;
    __syncthreads();  // also orders all LDS histogram atomics before flush
    if (threadIdx.x == 0) unsafeAtomicAdd(&ws[3], rV[0] + rV[1] + rV[2] + rV[3]);
    if (threadIdx.x < BINS) {
        float c = 0.f, s = 0.f;
        for (int k = 0; k < NCOPY; ++k) {
            c += s_cnt[k * SSTR + threadIdx.x];
            s += s_sum[k * SSTR + threadIdx.x];
        }
        unsafeAtomicAdd(&ws[4 + threadIdx.x], c);
        unsafeAtomicAdd(&ws[14 + threadIdx.x], s);
    }
}

__global__ void k_final(const float* __restrict__ ws, float* __restrict__ out) {
    if (threadIdx.x == 0 && blockIdx.x == 0) {
        float S   = ws[1] + ws[2];
        float tot = fmaxf(ws[3], 1.0f);
        int nne = 0;
        for (int b = 0; b < BINS; ++b) nne += (ws[4 + b] > 0.f) ? 1 : 0;
        float nn = fmaxf((float)nne, 1.0f);
        float wsum = 0.f;
        for (int b = 0; b < BINS; ++b) {
            float c = fmaxf(ws[4 + b], 1.0f);
            wsum += ws[14 + b] * (tot / c);   // binsum already carries 2*p*t
        }
        wsum /= nn;
        out[0] = 1.0f - wsum / S;
    }
}

extern "C" void kernel_launch(void* const* d_in, const int* in_sizes, int n_in,
                              void* d_out, int out_size, void* d_ws, size_t ws_size,
                              hipStream_t stream) {
    const float* p  = (const float*)d_in[0];
    const float* t  = (const float*)d_in[1];
    const float* lw = (const float*)d_in[2];
    float* ws  = (float*)d_ws;
    float* out = (float*)d_out;
    int n  = in_sizes[0];
    int n4 = n >> 2;

    hipMemsetAsync(d_ws, 0, (4 + 2 * BINS) * sizeof(float), stream);

    const int blocks = 2048;  // 8 blocks/CU, 16 float4-iters/thread at N=33.5M
    k_reduce1<<<blocks, 256, 0, stream>>>((const float4*)p, (const float4*)t, ws, n4, n);
    k_pass2<<<blocks, 256, 0, stream>>>((const float4*)p, (const float4*)t,
                                        (const float4*)lw, ws, n4, n);
    k_final<<<1, 64, 0, stream>>>(ws, out);
}

// Round 3
// 454.251 us; speedup vs baseline: 1.5442x; 1.5442x over previous
//
#include <hip/hip_runtime.h>

// GHM Dice loss, 3 passes:
//  k_reduce1: I = sum(p*t), sumP, sumT                        (reads p,t)
//  k_pass2:   histogram counts[10] + binsum[10] of 2*p*t, tot (reads p,t,lw)
//  k_final:   combine scalars -> loss
//
// Round-3 change: k_pass2 histogram moved from LDS atomics to PER-THREAD
// REGISTER bins. Rounds 1-2 were stuck at 333 us with VALUBusy 3.6%, hbm 7.6%,
// bank conflicts 0 -> wave-level LDS atomics are lane-serialized (~195 cyc per
// wave-level ds_add = 64 lanes x ~3 cyc; 4096 of them/CU = the whole 800K-cyc
// duration). Register bins + unrolled select cost ~50 VALU/element, well under
// the memory floor. Block reduce via non-atomic LDS transpose (stride 21,
// coprime with 32 banks -> free 2-lane aliasing).
//
// ws layout (floats): [0]=I [1]=sumP [2]=sumT [3]=tot [4..13]=counts [14..23]=binsum

constexpr int BINS = 10;

__global__ __launch_bounds__(256) void k_reduce1(const float4* __restrict__ p,
                                                 const float4* __restrict__ t,
                                                 float* __restrict__ ws,
                                                 int n4, int n) {
    int idx    = blockIdx.x * blockDim.x + threadIdx.x;
    int stride = gridDim.x * blockDim.x;
    float sI = 0.f, sP = 0.f, sT = 0.f;
#pragma unroll 4
    for (int i = idx; i < n4; i += stride) {
        float4 pv = p[i];
        float4 tv = t[i];
        sI += pv.x * tv.x + pv.y * tv.y + pv.z * tv.z + pv.w * tv.w;
        sP += pv.x + pv.y + pv.z + pv.w;
        sT += tv.x + tv.y + tv.z + tv.w;
    }
    if (idx == 0) {  // scalar tail (n not multiple of 4)
        const float* pf = (const float*)p;
        const float* tf = (const float*)t;
        for (int i = n4 * 4; i < n; ++i) { sI += pf[i] * tf[i]; sP += pf[i]; sT += tf[i]; }
    }
#pragma unroll
    for (int o = 32; o > 0; o >>= 1) {
        sI += __shfl_down(sI, o);
        sP += __shfl_down(sP, o);
        sT += __shfl_down(sT, o);
    }
    __shared__ float rI[4], rP[4], rT[4];
    int wave = threadIdx.x >> 6, lane = threadIdx.x & 63;
    if (lane == 0) { rI[wave] = sI; rP[wave] = sP; rT[wave] = sT; }
    __syncthreads();
    if (threadIdx.x == 0) {
        unsafeAtomicAdd(&ws[0], rI[0] + rI[1] + rI[2] + rI[3]);
        unsafeAtomicAdd(&ws[1], rP[0] + rP[1] + rP[2] + rP[3]);
        unsafeAtomicAdd(&ws[2], rT[0] + rT[1] + rT[2] + rT[3]);
    }
}

__global__ __launch_bounds__(256) void k_pass2(const float4* __restrict__ p,
                                               const float4* __restrict__ t,
                                               const float4* __restrict__ lw,
                                               float* __restrict__ ws,
                                               int n4, int n) {
    const float scale    = 2.f * ws[0] / (ws[1] + ws[2]);  // 2I/S
    const float edge_top = 1.0f + 1e-6f;

    // Per-thread register histogram — all indexing is compile-time constant
    // (unrolled), so these stay in VGPRs, never scratch.
    float cnt[BINS], sm[BINS];
#pragma unroll
    for (int b = 0; b < BINS; ++b) { cnt[b] = 0.f; sm[b] = 0.f; }
    float vcount = 0.f;

    int idx    = blockIdx.x * blockDim.x + threadIdx.x;
    int stride = gridDim.x * blockDim.x;

    for (int i = idx; i < n4; i += stride) {
        float4 pv = p[i], tv = t[i], wv = lw[i];
        float pj[4] = {pv.x, pv.y, pv.z, pv.w};
        float tj[4] = {tv.x, tv.y, tv.z, tv.w};
        float wj[4] = {wv.x, wv.y, wv.z, wv.w};
#pragma unroll
        for (int j = 0; j < 4; ++j) {
            bool valid = wj[j] > 0.f;
            vcount += valid ? 1.f : 0.f;
            float g = fabsf(scale * pj[j] - tj[j]);
            bool inr = valid && (g < edge_top);
            int b = (int)(g * 10.f);          // g >= 0, trunc == floor
            b = b > (BINS - 1) ? (BINS - 1) : b;
            float addc = inr ? 1.f : 0.f;
            float adds = inr ? 2.f * pj[j] * tj[j] : 0.f;
#pragma unroll
            for (int b0 = 0; b0 < BINS; ++b0) {
                bool m = (b == b0);
                cnt[b0] += m ? addc : 0.f;
                sm[b0]  += m ? adds : 0.f;
            }
        }
    }
    if (idx == 0) {  // scalar tail
        const float* pf = (const float*)p;
        const float* tf = (const float*)t;
        const float* wf = (const float*)lw;
        for (int i = n4 * 4; i < n; ++i) {
            bool valid = wf[i] > 0.f;
            vcount += valid ? 1.f : 0.f;
            float g = fabsf(scale * pf[i] - tf[i]);
            bool inr = valid && (g < edge_top);
            int b = (int)(g * 10.f);
            b = b > (BINS - 1) ? (BINS - 1) : b;
            float addc = inr ? 1.f : 0.f;
            float adds = inr ? 2.f * pf[i] * tf[i] : 0.f;
#pragma unroll
            for (int b0 = 0; b0 < BINS; ++b0) {
                bool m = (b == b0);
                cnt[b0] += m ? addc : 0.f;
                sm[b0]  += m ? adds : 0.f;
            }
        }
    }

    // Block reduction: plain LDS transpose, no atomics, no shuffles.
    // Layout [tid][21]: stride 21 coprime with 32 banks -> 2 lanes/bank (free).
    __shared__ float red[256 * 21];
    float* mine = &red[threadIdx.x * 21];
#pragma unroll
    for (int b0 = 0; b0 < BINS; ++b0) { mine[b0] = cnt[b0]; mine[BINS + b0] = sm[b0]; }
    mine[2 * BINS] = vcount;
    __syncthreads();

    int tid = threadIdx.x;
    if (tid < 2 * BINS + 1) {
        float v = 0.f;
        for (int i = 0; i < 256; ++i) v += red[i * 21 + tid];
        if (tid < BINS)           unsafeAtomicAdd(&ws[4 + tid], v);
        else if (tid < 2 * BINS)  unsafeAtomicAdd(&ws[14 + (tid - BINS)], v);
        else                      unsafeAtomicAdd(&ws[3], v);
    }
}

__global__ void k_final(const float* __restrict__ ws, float* __restrict__ out) {
    if (threadIdx.x == 0 && blockIdx.x == 0) {
        float S   = ws[1] + ws[2];
        float tot = fmaxf(ws[3], 1.0f);
        int nne = 0;
        for (int b = 0; b < BINS; ++b) nne += (ws[4 + b] > 0.f) ? 1 : 0;
        float nn = fmaxf((float)nne, 1.0f);
        float wsum = 0.f;
        for (int b = 0; b < BINS; ++b) {
            float c = fmaxf(ws[4 + b], 1.0f);
            wsum += ws[14 + b] * (tot / c);   // binsum already carries 2*p*t
        }
        wsum /= nn;
        out[0] = 1.0f - wsum / S;
    }
}

extern "C" void kernel_launch(void* const* d_in, const int* in_sizes, int n_in,
                              void* d_out, int out_size, void* d_ws, size_t ws_size,
                              hipStream_t stream) {
    const float* p  = (const float*)d_in[0];
    const float* t  = (const float*)d_in[1];
    const float* lw = (const float*)d_in[2];
    float* ws  = (float*)d_ws;
    float* out = (float*)d_out;
    int n  = in_sizes[0];
    int n4 = n >> 2;

    hipMemsetAsync(d_ws, 0, (4 + 2 * BINS) * sizeof(float), stream);

    const int blocks = 2048;  // 8 blocks/CU, 16 float4-iters/thread at N=33.5M
    k_reduce1<<<blocks, 256, 0, stream>>>((const float4*)p, (const float4*)t, ws, n4, n);
    k_pass2<<<blocks, 256, 0, stream>>>((const float4*)p, (const float4*)t,
                                        (const float4*)lw, ws, n4, n);
    k_final<<<1, 64, 0, stream>>>(ws, out);
}